// Round 16
// baseline (26.972 us; speedup 1.0000x reference)
//
#include <hip/hip_runtime.h>

namespace {

constexpr int IMGSZ = 224;
constexpr int IMG2  = IMGSZ * IMGSZ;   // 50176

// Champion (25.56us: A/A-verified + heavy-first + coalesced lane map) with
// ONE change: EXACT-BOUND table fills.
//   u-fill: one masked iteration (28 entries, window [16+r0-12, 16+r0+16)
//           covering every read index 16+r0+r-oy in [16+r0-11, 16+r0+15]).
//   v-fill: bound = 4*NCB2+12 floats (max read = vt4[cb+3].w = 4*NCB2+11),
//           so G=12/23 pay 1 iteration, G=68 2, G=135 3 (was 3 for all).
// Everything else byte-identical. Per WAVE (2 waves/block, no barriers):
// row = lane>>2, seg = wv*4 + (lane&3); each 4-lane group reads a contiguous
// 64B row segment (coalesced). H[row][ox] = sum_c S[row][c]*v[c-ox] via
// compile-time register window vs the LDS v-table (pre-shifted by sh).
// Reduce 4 segs (shfl {2,1}, association matches old {32,16} bitwise) ->
// per-wave H in LDS -> per-wave vertical partial -> atomicAdd.
// k = u v^T (rank-1 bicubic): u[r] = k[r][c0], v[c] = k[c0][c] / k[c0][c0].
template <int G>
__device__ void chunk_glimpse(
    int b, int gi, int ch,
    const float* __restrict__ img, const int* __restrict__ locs,
    const float* __restrict__ kptr, float* __restrict__ out,
    float* __restrict__ vpad2, float* __restrict__ upad,
    float (*__restrict__ h_lds)[12]) {
  constexpr int KSZ   = G - 11;
  constexpr int C0    = KSZ / 2;
  constexpr int NCB2  = (G + 2) / 4 + 1;   // aligned 4-col blocks (covers sh<=3)
  constexpr int VFILL = 4 * NCB2 + 12;     // max v-table float read is 4*NCB2+11
  const int lane = threadIdx.x & 63;
  const int r0 = ch * 16;

  const int x = locs[2 * b];
  const int y = locs[2 * b + 1];
  const int row0 = x - G / 2 + r0;
  const int col0 = y - G / 2;
  const int sh = col0 & 3;                 // floor-mod 4 (works for negative)
  const int col_a0 = col0 - sh;            // image-aligned start (16B aligned)
  const int R = (G - r0) < 16 ? (G - r0) : 16;
  const float* imgb = img + (size_t)b * (3 * IMG2);

  // per-wave v table (exact bound): vpad2[i] = v[i - 11 - sh], 0 outside
  {
    const float rpiv = 1.0f / kptr[C0 * KSZ + C0];
    for (int i = lane; i < VFILL; i += 64) {
      const int k = i - 11 - sh;
      vpad2[i] = (k >= 0 && k < KSZ) ? kptr[C0 * KSZ + k] * rpiv : 0.f;
    }
  }
  // per-wave u table (exact window, single masked iteration):
  // reads span upad[16+r0-11 .. 16+r0+15]; fill [16+r0-12, 16+r0+16)
  if (lane < 28) {
    const int i = 16 + r0 - 12 + lane;     // 4 <= i <= 159
    const int j = i - 16;
    upad[i] = (j >= 0 && j < KSZ) ? kptr[j * KSZ + C0] : 0.f;
  }

  const int row = lane >> 2;                            // 0..15
  const int seg = (threadIdx.x >> 6) * 4 + (lane & 3);  // 0..7

  float acc[12];
  #pragma unroll
  for (int i = 0; i < 12; ++i) acc[i] = 0.f;

  const int grow = row0 + row;
  if (row < R && (unsigned)grow < (unsigned)IMGSZ) {
    const float* prow = imgb + grow * IMGSZ;
    const int cend = col0 + G;
    for (int cb = seg; cb < NCB2; cb += 8) {
      const int cbase = col_a0 + 4 * cb;
      if (cbase >= cend) break;
      float sj[4];
      if (cbase >= 0 && cbase <= IMGSZ - 4) {
        const float4 a  = *reinterpret_cast<const float4*>(prow + cbase);
        const float4 b4 = *reinterpret_cast<const float4*>(prow + IMG2 + cbase);
        const float4 c4 = *reinterpret_cast<const float4*>(prow + 2 * IMG2 + cbase);
        sj[0] = a.x + b4.x + c4.x;
        sj[1] = a.y + b4.y + c4.y;
        sj[2] = a.z + b4.z + c4.z;
        sj[3] = a.w + b4.w + c4.w;
      } else {
        #pragma unroll
        for (int j = 0; j < 4; ++j) {
          const int cc = cbase + j;
          sj[j] = ((unsigned)cc < (unsigned)IMGSZ)
                      ? prow[cc] + prow[IMG2 + cc] + prow[2 * IMG2 + cc]
                      : 0.f;
        }
      }
      float vv[16];
      #pragma unroll
      for (int q = 0; q < 4; ++q) {
        const float4 v4 = *reinterpret_cast<const float4*>(vpad2 + 4 * cb + 4 * q);
        vv[q * 4 + 0] = v4.x; vv[q * 4 + 1] = v4.y;
        vv[q * 4 + 2] = v4.z; vv[q * 4 + 3] = v4.w;
      }
      #pragma unroll
      for (int j = 0; j < 4; ++j) {
        #pragma unroll
        for (int ox = 0; ox < 12; ++ox) {
          acc[ox] += sj[j] * vv[11 + j - ox];   // = v[c_rel - ox], c_rel = 4cb+j-sh
        }
      }
    }
  }

  // reduce 4 segs within each 4-lane group (segs at lane strides of 1;
  // association (s0+s2)+(s1+s3) matches the old {32,16} order bitwise)
  #pragma unroll
  for (int ox = 0; ox < 12; ++ox) {
    acc[ox] += __shfl_down(acc[ox], 2, 64);
    acc[ox] += __shfl_down(acc[ox], 1, 64);
  }
  if ((lane & 3) == 0) {
    #pragma unroll
    for (int ox = 0; ox < 12; ++ox) h_lds[lane >> 2][ox] = acc[ox];
  }
  // same-wave LDS write->read: ordered by hardware waitcnt, no barrier needed

  // per-wave vertical partial -> atomic scatter
  float* outp = out + ((size_t)b * 4 + gi) * 144;
  for (int e = lane; e < 144; e += 64) {
    const int oy = e / 12;
    const int ox = e - oy * 12;
    float s = 0.f;
    #pragma unroll
    for (int r = 0; r < 16; ++r) {
      s += upad[16 + r0 + r - oy] * h_lds[r][ox];
    }
    atomicAdd(&outp[e], s);
  }
}

__global__ __launch_bounds__(128, 6) void glimpse_kernel(
    const float* __restrict__ img, const int* __restrict__ locs,
    const float* __restrict__ k0, const float* __restrict__ k1,
    const float* __restrict__ k2, const float* __restrict__ k3,
    float* __restrict__ out) {
  __shared__ __align__(16) float vpad2[2][176];
  __shared__ __align__(16) float upad[2][160];
  __shared__ float h_lds[2][16][12];
  const int bid = blockIdx.x;
  const int b = bid & 255;
  const int t = 16 - (bid >> 8);     // heavy-first: G=135 chunks dispatch first
  const int wv = threadIdx.x >> 6;
  if (t == 0) {
    chunk_glimpse<12 >(b, 0, 0,     img, locs, k0, out, vpad2[wv], upad[wv], h_lds[wv]);
  } else if (t < 3) {
    chunk_glimpse<23 >(b, 1, t - 1, img, locs, k1, out, vpad2[wv], upad[wv], h_lds[wv]);
  } else if (t < 8) {
    chunk_glimpse<68 >(b, 2, t - 3, img, locs, k2, out, vpad2[wv], upad[wv], h_lds[wv]);
  } else {
    chunk_glimpse<135>(b, 3, t - 8, img, locs, k3, out, vpad2[wv], upad[wv], h_lds[wv]);
  }
}

}  // namespace

extern "C" void kernel_launch(void* const* d_in, const int* in_sizes, int n_in,
                              void* d_out, int out_size, void* d_ws, size_t ws_size,
                              hipStream_t stream) {
  const float* img  = (const float*)d_in[0];
  const int*   locs = (const int*)d_in[1];
  const float* k0   = (const float*)d_in[2];
  const float* k1   = (const float*)d_in[3];
  const float* k2   = (const float*)d_in[4];
  const float* k3   = (const float*)d_in[5];
  float* out = (float*)d_out;

  hipMemsetAsync(out, 0, (size_t)out_size * sizeof(float), stream);
  glimpse_kernel<<<256 * 17, 128, 0, stream>>>(img, locs, k0, k1, k2, k3, out);
}

// Round 17
// 25.520 us; speedup vs baseline: 1.0569x; 1.0569x over previous
//
#include <hip/hip_runtime.h>

namespace {

constexpr int IMGSZ = 224;
constexpr int IMG2  = IMGSZ * IMGSZ;   // 50176

// Champion (25.56us: A/A-verified + heavy-first + coalesced lane map) with
// ONE change: __launch_bounds__(128, 4) (was (128, 6)) -> VGPR cap 128
// instead of ~85, testing whether the allocator was spilling/contorting
// under the tighter cap. Everything else byte-identical.
// One block = (b, 16-row chunk of one glimpse). Per WAVE (2 waves/block, no
// __syncthreads anywhere): row = lane>>2, seg = wv*4 + (lane&3); each 4-lane
// group reads a contiguous 64B row segment (coalesced image-aligned float4s,
// channel-summed). H[row][ox] = sum_c S[row][c] * v[c-ox] via compile-time
// register window against an LDS v-table pre-shifted by sh = col0 & 3.
// Reduce 4 segs (shfl {2,1}, association matches old {32,16} bitwise) ->
// per-wave H partial in LDS -> per-wave vertical partial
// out[oy][ox] += sum_r u[r0+r-oy]*H[r][ox] via atomicAdd (<=18 per address).
// k = u v^T (rank-1 bicubic): u[r] = k[r][c0], v[c] = k[c0][c] / k[c0][c0].
template <int G>
__device__ void chunk_glimpse(
    int b, int gi, int ch,
    const float* __restrict__ img, const int* __restrict__ locs,
    const float* __restrict__ kptr, float* __restrict__ out,
    float* __restrict__ vpad2, float* __restrict__ upad,
    float (*__restrict__ h_lds)[12]) {
  constexpr int KSZ  = G - 11;
  constexpr int C0   = KSZ / 2;
  constexpr int NCB2 = (G + 2) / 4 + 1;    // aligned 4-col blocks (covers sh<=3)
  const int lane = threadIdx.x & 63;
  const int r0 = ch * 16;

  const int x = locs[2 * b];
  const int y = locs[2 * b + 1];
  const int row0 = x - G / 2 + r0;
  const int col0 = y - G / 2;
  const int sh = col0 & 3;                 // floor-mod 4 (works for negative)
  const int col_a0 = col0 - sh;            // image-aligned start (16B aligned)
  const int R = (G - r0) < 16 ? (G - r0) : 16;
  const float* imgb = img + (size_t)b * (3 * IMG2);

  // per-wave v table: vpad2[i] = v[i - 11 - sh], zeros outside [0,KSZ)
  {
    const float rpiv = 1.0f / kptr[C0 * KSZ + C0];
    for (int i = lane; i < 176; i += 64) {
      const int k = i - 11 - sh;
      vpad2[i] = (k >= 0 && k < KSZ) ? kptr[C0 * KSZ + k] * rpiv : 0.f;
    }
  }
  // per-wave u table: upad[16+j] = u[j], zeros outside
  for (int i = lane; i < 160; i += 64) {
    const int j = i - 16;
    upad[i] = (j >= 0 && j < KSZ) ? kptr[j * KSZ + C0] : 0.f;
  }

  const int row = lane >> 2;                            // 0..15
  const int seg = (threadIdx.x >> 6) * 4 + (lane & 3);  // 0..7

  float acc[12];
  #pragma unroll
  for (int i = 0; i < 12; ++i) acc[i] = 0.f;

  const int grow = row0 + row;
  if (row < R && (unsigned)grow < (unsigned)IMGSZ) {
    const float* prow = imgb + grow * IMGSZ;
    const int cend = col0 + G;
    for (int cb = seg; cb < NCB2; cb += 8) {
      const int cbase = col_a0 + 4 * cb;
      if (cbase >= cend) break;
      float sj[4];
      if (cbase >= 0 && cbase <= IMGSZ - 4) {
        const float4 a  = *reinterpret_cast<const float4*>(prow + cbase);
        const float4 b4 = *reinterpret_cast<const float4*>(prow + IMG2 + cbase);
        const float4 c4 = *reinterpret_cast<const float4*>(prow + 2 * IMG2 + cbase);
        sj[0] = a.x + b4.x + c4.x;
        sj[1] = a.y + b4.y + c4.y;
        sj[2] = a.z + b4.z + c4.z;
        sj[3] = a.w + b4.w + c4.w;
      } else {
        #pragma unroll
        for (int j = 0; j < 4; ++j) {
          const int cc = cbase + j;
          sj[j] = ((unsigned)cc < (unsigned)IMGSZ)
                      ? prow[cc] + prow[IMG2 + cc] + prow[2 * IMG2 + cc]
                      : 0.f;
        }
      }
      float vv[16];
      #pragma unroll
      for (int q = 0; q < 4; ++q) {
        const float4 v4 = *reinterpret_cast<const float4*>(vpad2 + 4 * cb + 4 * q);
        vv[q * 4 + 0] = v4.x; vv[q * 4 + 1] = v4.y;
        vv[q * 4 + 2] = v4.z; vv[q * 4 + 3] = v4.w;
      }
      #pragma unroll
      for (int j = 0; j < 4; ++j) {
        #pragma unroll
        for (int ox = 0; ox < 12; ++ox) {
          acc[ox] += sj[j] * vv[11 + j - ox];   // = v[c_rel - ox], c_rel = 4cb+j-sh
        }
      }
    }
  }

  // reduce 4 segs within each 4-lane group (segs at lane strides of 1;
  // association (s0+s2)+(s1+s3) matches the old {32,16} order bitwise)
  #pragma unroll
  for (int ox = 0; ox < 12; ++ox) {
    acc[ox] += __shfl_down(acc[ox], 2, 64);
    acc[ox] += __shfl_down(acc[ox], 1, 64);
  }
  if ((lane & 3) == 0) {
    #pragma unroll
    for (int ox = 0; ox < 12; ++ox) h_lds[lane >> 2][ox] = acc[ox];
  }
  // same-wave LDS write->read: ordered by hardware waitcnt, no barrier needed

  // per-wave vertical partial -> atomic scatter
  float* outp = out + ((size_t)b * 4 + gi) * 144;
  for (int e = lane; e < 144; e += 64) {
    const int oy = e / 12;
    const int ox = e - oy * 12;
    float s = 0.f;
    #pragma unroll
    for (int r = 0; r < 16; ++r) {
      s += upad[16 + r0 + r - oy] * h_lds[r][ox];
    }
    atomicAdd(&outp[e], s);
  }
}

__global__ __launch_bounds__(128, 4) void glimpse_kernel(
    const float* __restrict__ img, const int* __restrict__ locs,
    const float* __restrict__ k0, const float* __restrict__ k1,
    const float* __restrict__ k2, const float* __restrict__ k3,
    float* __restrict__ out) {
  __shared__ __align__(16) float vpad2[2][176];
  __shared__ __align__(16) float upad[2][160];
  __shared__ float h_lds[2][16][12];
  const int bid = blockIdx.x;
  const int b = bid & 255;
  const int t = 16 - (bid >> 8);     // heavy-first: G=135 chunks dispatch first
  const int wv = threadIdx.x >> 6;
  if (t == 0) {
    chunk_glimpse<12 >(b, 0, 0,     img, locs, k0, out, vpad2[wv], upad[wv], h_lds[wv]);
  } else if (t < 3) {
    chunk_glimpse<23 >(b, 1, t - 1, img, locs, k1, out, vpad2[wv], upad[wv], h_lds[wv]);
  } else if (t < 8) {
    chunk_glimpse<68 >(b, 2, t - 3, img, locs, k2, out, vpad2[wv], upad[wv], h_lds[wv]);
  } else {
    chunk_glimpse<135>(b, 3, t - 8, img, locs, k3, out, vpad2[wv], upad[wv], h_lds[wv]);
  }
}

}  // namespace

extern "C" void kernel_launch(void* const* d_in, const int* in_sizes, int n_in,
                              void* d_out, int out_size, void* d_ws, size_t ws_size,
                              hipStream_t stream) {
  const float* img  = (const float*)d_in[0];
  const int*   locs = (const int*)d_in[1];
  const float* k0   = (const float*)d_in[2];
  const float* k1   = (const float*)d_in[3];
  const float* k2   = (const float*)d_in[4];
  const float* k3   = (const float*)d_in[5];
  float* out = (float*)d_out;

  hipMemsetAsync(out, 0, (size_t)out_size * sizeof(float), stream);
  glimpse_kernel<<<256 * 17, 128, 0, stream>>>(img, locs, k0, k1, k2, k3, out);
}